// Round 1
// baseline (635.242 us; speedup 1.0000x reference)
//
#include <hip/hip_runtime.h>
#include <cstdint>
#include <cstddef>

#define Bb 8
#define Tt 2048
#define Cc 1024
#define Ss 256

using short8 = __attribute__((ext_vector_type(8))) short;
using f32x4  = __attribute__((ext_vector_type(4))) float;

// round-to-nearest-even fp32 -> bf16 (bit pattern)
__device__ __forceinline__ unsigned short f2bf(float f) {
  unsigned int u = __float_as_uint(f);
  u += 0x7fffu + ((u >> 16) & 1u);
  return (unsigned short)(u >> 16);
}

// slots[b,s,c] = mean over 8 consecutive t rows
__global__ __launch_bounds__(256) void pool_k(const float* __restrict__ x, float* __restrict__ slots) {
  int id = blockIdx.x * 256 + threadIdx.x;   // over B*S*(C/4) = 524288
  int c  = (id & 255) << 2;
  int sl = id >> 8;                          // b*S + s
  int b = sl >> 8, s = sl & 255;
  const float* src = x + ((size_t)b * Tt + s * 8) * Cc + c;
  float ax = 0.f, ay = 0.f, az = 0.f, aw = 0.f;
#pragma unroll
  for (int j = 0; j < 8; j++) {
    float4 v = *(const float4*)(src + (size_t)j * Cc);
    ax += v.x; ay += v.y; az += v.z; aw += v.w;
  }
  float4 o = make_float4(ax * 0.125f, ay * 0.125f, az * 0.125f, aw * 0.125f);
  *(float4*)(slots + (size_t)sl * Cc + c) = o;
}

// fp32 tiled GEMM, 64x64x16 tile, 4x4 microtile. All row strides are 1024, K=1024.
// ATRANS: A stored [M][K] (needs transpose staging); else A stored [K][M].
// BTRANS: B stored [N][K]; else [K][N].
template<int ATRANS, int BTRANS>
__global__ __launch_bounds__(256) void gemm_f32(const float* __restrict__ A, const float* __restrict__ Bm,
                                                float* __restrict__ C) {
  __shared__ float As[16][68];
  __shared__ float Bs[16][68];
  const int tid = threadIdx.x;
  const int m0 = blockIdx.y << 6, n0 = blockIdx.x << 6;
  const int tx = tid & 15, ty = tid >> 4;
  float acc[4][4] = {};
  for (int k0 = 0; k0 < Cc; k0 += 16) {
    __syncthreads();
    if (ATRANS) {
      int m = tid >> 2, k4 = (tid & 3) << 2;
      float4 av = *(const float4*)&A[(size_t)(m0 + m) * Cc + k0 + k4];
      As[k4 + 0][m] = av.x; As[k4 + 1][m] = av.y; As[k4 + 2][m] = av.z; As[k4 + 3][m] = av.w;
    } else {
      int kk = tid >> 4, m4 = (tid & 15) << 2;
      *(float4*)&As[kk][m4] = *(const float4*)&A[(size_t)(k0 + kk) * Cc + m0 + m4];
    }
    if (BTRANS) {
      int n = tid >> 2, k4 = (tid & 3) << 2;
      float4 bv = *(const float4*)&Bm[(size_t)(n0 + n) * Cc + k0 + k4];
      Bs[k4 + 0][n] = bv.x; Bs[k4 + 1][n] = bv.y; Bs[k4 + 2][n] = bv.z; Bs[k4 + 3][n] = bv.w;
    } else {
      int kk = tid >> 4, n4 = (tid & 15) << 2;
      *(float4*)&Bs[kk][n4] = *(const float4*)&Bm[(size_t)(k0 + kk) * Cc + n0 + n4];
    }
    __syncthreads();
#pragma unroll
    for (int kk = 0; kk < 16; kk++) {
      float4 a = *(const float4*)&As[kk][ty << 2];
      float4 b = *(const float4*)&Bs[kk][tx << 2];
      const float aa[4] = {a.x, a.y, a.z, a.w};
      const float bb[4] = {b.x, b.y, b.z, b.w};
#pragma unroll
      for (int i = 0; i < 4; i++)
#pragma unroll
        for (int j = 0; j < 4; j++)
          acc[i][j] = fmaf(aa[i], bb[j], acc[i][j]);
    }
  }
#pragma unroll
  for (int i = 0; i < 4; i++) {
    float4 o = make_float4(acc[i][0], acc[i][1], acc[i][2], acc[i][3]);
    *(float4*)&C[(size_t)(m0 + (ty << 2) + i) * Cc + n0 + (tx << 2)] = o;
  }
}

// scores = x @ kq^T / 32 for one (b, 64-row t-tile), fused top-8 + softmax.
// Thread (tx=tid&31, ty=tid>>5) owns rows {ty*4+i, 32+ty*4+i} and cols s = tx + 32*c.
__global__ __launch_bounds__(256) void scores_topk_k(const float* __restrict__ x, const float* __restrict__ kq,
                                                     float* __restrict__ topw, int* __restrict__ topi) {
  __shared__ float xs[8][68];
  __shared__ float kqs[8][260];
  const int tid = threadIdx.x;
  const int tt = blockIdx.x, b = blockIdx.y;
  const int tx = tid & 31, ty = tid >> 5;
  const float* xb  = x  + ((size_t)b * Tt + tt * 64) * Cc;
  const float* kqb = kq + (size_t)b * Ss * Cc;
  float acc[8][8] = {};
  for (int k0 = 0; k0 < Cc; k0 += 8) {
    __syncthreads();
    if (tid < 128) {
      int m = tid >> 1, k4 = (tid & 1) << 2;
      float4 av = *(const float4*)&xb[(size_t)m * Cc + k0 + k4];
      xs[k4 + 0][m] = av.x; xs[k4 + 1][m] = av.y; xs[k4 + 2][m] = av.z; xs[k4 + 3][m] = av.w;
    }
#pragma unroll
    for (int h = 0; h < 2; h++) {
      int ch = tid + (h << 8);
      int s = ch >> 1, k4 = (ch & 1) << 2;
      float4 bv = *(const float4*)&kqb[(size_t)s * Cc + k0 + k4];
      kqs[k4 + 0][s] = bv.x; kqs[k4 + 1][s] = bv.y; kqs[k4 + 2][s] = bv.z; kqs[k4 + 3][s] = bv.w;
    }
    __syncthreads();
#pragma unroll
    for (int kk = 0; kk < 8; kk++) {
      float xv[8], kv[8];
      float4 xa = *(const float4*)&xs[kk][ty << 2];
      float4 xc = *(const float4*)&xs[kk][32 + (ty << 2)];
      xv[0] = xa.x; xv[1] = xa.y; xv[2] = xa.z; xv[3] = xa.w;
      xv[4] = xc.x; xv[5] = xc.y; xv[6] = xc.z; xv[7] = xc.w;
#pragma unroll
      for (int c2 = 0; c2 < 8; c2++) kv[c2] = kqs[kk][tx + (c2 << 5)];
#pragma unroll
      for (int i = 0; i < 8; i++)
#pragma unroll
        for (int c2 = 0; c2 < 8; c2++)
          acc[i][c2] = fmaf(xv[i], kv[c2], acc[i][c2]);
    }
  }
  // per-row top-8 (lower index wins ties) + softmax, within each 32-lane half-wave
#pragma unroll
  for (int i = 0; i < 8; i++) {
    const int rloc = (i < 4) ? ((ty << 2) + i) : (32 + (ty << 2) + (i - 4));
    float tmp[8];
#pragma unroll
    for (int c2 = 0; c2 < 8; c2++) tmp[c2] = acc[i][c2] * 0.03125f;  // 1/sqrt(1024)
    float topv[8]; int tops[8];
#pragma unroll
    for (int k = 0; k < 8; k++) {
      float bv = -1e30f; int bs = 1 << 20;
#pragma unroll
      for (int c2 = 0; c2 < 8; c2++) {
        float v = tmp[c2]; int s = tx + (c2 << 5);
        if (v > bv || (v == bv && s < bs)) { bv = v; bs = s; }
      }
#pragma unroll
      for (int m = 16; m >= 1; m >>= 1) {
        float ov = __shfl_xor(bv, m, 64);
        int   os = __shfl_xor(bs, m, 64);
        if (ov > bv || (ov == bv && os < bs)) { bv = ov; bs = os; }
      }
      topv[k] = bv; tops[k] = bs;
#pragma unroll
      for (int c2 = 0; c2 < 8; c2++)
        if (((bs >> 5) == c2) && ((bs & 31) == tx)) tmp[c2] = -1e30f;
    }
    float mx = topv[0];
    float sum = 0.f;
#pragma unroll
    for (int k = 0; k < 8; k++) sum += expf(topv[k] - mx);
    if (tx < 8) {
      float myv = topv[0]; int myi = tops[0];
#pragma unroll
      for (int k = 1; k < 8; k++) if (tx == k) { myv = topv[k]; myi = tops[k]; }
      size_t row = (size_t)b * Tt + (size_t)tt * 64 + rloc;
      topw[row * 8 + tx] = expf(myv - mx) / sum;
      topi[row * 8 + tx] = myi;
    }
  }
}

// retrieved[row, :] = sum_k w_k * v[b, idx_k, :]  -> bf16
__global__ __launch_bounds__(256) void gather_k(const float* __restrict__ v, const float* __restrict__ topw,
                                                const int* __restrict__ topi, unsigned short* __restrict__ retr) {
  __shared__ float w[8];
  __shared__ int  id8[8];
  const int row = blockIdx.x;
  const int b = row >> 11;
  if (threadIdx.x < 8) {
    w[threadIdx.x]   = topw[(size_t)row * 8 + threadIdx.x];
    id8[threadIdx.x] = topi[(size_t)row * 8 + threadIdx.x];
  }
  __syncthreads();
  int c = threadIdx.x << 2;
  float ax = 0.f, ay = 0.f, az = 0.f, aw = 0.f;
#pragma unroll
  for (int j = 0; j < 8; j++) {
    const float4 vv = *(const float4*)&v[((size_t)(b << 8) + id8[j]) * Cc + c];
    float wj = w[j];
    ax = fmaf(wj, vv.x, ax); ay = fmaf(wj, vv.y, ay);
    az = fmaf(wj, vv.z, az); aw = fmaf(wj, vv.w, aw);
  }
  uint2 o;
  o.x = (unsigned)f2bf(ax) | ((unsigned)f2bf(ay) << 16);
  o.y = (unsigned)f2bf(az) | ((unsigned)f2bf(aw) << 16);
  *(uint2*)&retr[(size_t)row * Cc + c] = o;
}

__global__ __launch_bounds__(256) void cvt_bf16_k(const float* __restrict__ src, unsigned short* __restrict__ dst) {
  int id = blockIdx.x * 256 + threadIdx.x;
  int c = id << 2;
  float4 v = *(const float4*)&src[c];
  uint2 o;
  o.x = (unsigned)f2bf(v.x) | ((unsigned)f2bf(v.y) << 16);
  o.y = (unsigned)f2bf(v.z) | ((unsigned)f2bf(v.w) << 16);
  *(uint2*)&dst[c] = o;
}

// out = 0.5 * retr @ Wp^T, bf16 MFMA 16x16x32, 128x128x32 tile, 4 waves of 64x64.
__global__ __launch_bounds__(256) void gemm_out_k(const unsigned short* __restrict__ A,
                                                  const unsigned short* __restrict__ Bw,
                                                  float* __restrict__ C) {
  __shared__ unsigned short As[128 * 40];  // row stride 40 shorts (pad 8) -> ~2-way bank conflicts
  __shared__ unsigned short Bs[128 * 40];
  const int tid = threadIdx.x;
  const int m0 = blockIdx.x << 7, n0 = blockIdx.y << 7;
  const int lane = tid & 63, wid = tid >> 6;
  const int wm = (wid >> 1) << 6, wn = (wid & 1) << 6;
  const int lm = lane & 15, lq = lane >> 4;
  const f32x4 zero = {0.f, 0.f, 0.f, 0.f};
  f32x4 acc[4][4];
#pragma unroll
  for (int i = 0; i < 4; i++)
#pragma unroll
    for (int j = 0; j < 4; j++) acc[i][j] = zero;

  for (int k0 = 0; k0 < Cc; k0 += 32) {
    __syncthreads();
#pragma unroll
    for (int h = 0; h < 2; h++) {
      int ch = tid + (h << 8);
      int r = ch >> 2, kg = (ch & 3) << 3;
      *(short8*)&As[r * 40 + kg] = *(const short8*)&A[(size_t)(m0 + r) * Cc + k0 + kg];
      *(short8*)&Bs[r * 40 + kg] = *(const short8*)&Bw[(size_t)(n0 + r) * Cc + k0 + kg];
    }
    __syncthreads();
    short8 af[4], bf[4];
#pragma unroll
    for (int i = 0; i < 4; i++) af[i] = *(const short8*)&As[(wm + (i << 4) + lm) * 40 + (lq << 3)];
#pragma unroll
    for (int j = 0; j < 4; j++) bf[j] = *(const short8*)&Bs[(wn + (j << 4) + lm) * 40 + (lq << 3)];
#pragma unroll
    for (int i = 0; i < 4; i++)
#pragma unroll
      for (int j = 0; j < 4; j++)
        acc[i][j] = __builtin_amdgcn_mfma_f32_16x16x32_bf16(af[i], bf[j], acc[i][j], 0, 0, 0);
  }
  // C/D layout: col = lane&15, row = (lane>>4)*4 + reg  [m89-verified]
#pragma unroll
  for (int i = 0; i < 4; i++)
#pragma unroll
    for (int j = 0; j < 4; j++)
#pragma unroll
      for (int r = 0; r < 4; r++) {
        int gr = m0 + wm + (i << 4) + (lq << 2) + r;
        int gc = n0 + wn + (j << 4) + lm;
        C[(size_t)gr * Cc + gc] = acc[i][j][r] * 0.5f;
      }
}

extern "C" void kernel_launch(void* const* d_in, const int* in_sizes, int n_in,
                              void* d_out, int out_size, void* d_ws, size_t ws_size,
                              hipStream_t stream) {
  (void)in_sizes; (void)n_in; (void)out_size; (void)ws_size;
  const float* x  = (const float*)d_in[0];
  const float* Wq = (const float*)d_in[1];
  const float* Wk = (const float*)d_in[2];
  const float* Wv = (const float*)d_in[3];
  const float* Wp = (const float*)d_in[4];
  float* out = (float*)d_out;

  char* ws = (char*)d_ws;
  float* slots = (float*)(ws);                               // 8 MB  [2048 x 1024]
  float* Mt    = (float*)(ws + (8ull  << 20));               // 4 MB  [1024 x 1024] = Wk^T Wq
  float* kq    = (float*)(ws + (12ull << 20));               // 8 MB  [2048 x 1024]
  float* vv    = (float*)(ws + (20ull << 20));               // 8 MB  [2048 x 1024]
  float* topw  = (float*)(ws + (28ull << 20));               // 0.5 MB [16384 x 8]
  int*   topi  = (int*)  (ws + (28ull << 20) + (512u << 10));// 0.5 MB
  unsigned short* retr = (unsigned short*)(ws + (29ull << 20)); // 32 MB [16384 x 1024] bf16
  unsigned short* WpB  = (unsigned short*)(ws + (61ull << 20)); // 2 MB bf16

  pool_k<<<2048, 256, 0, stream>>>(x, slots);
  gemm_f32<0, 0><<<dim3(16, 16), 256, 0, stream>>>(Wk, Wq, Mt);    // Mt[e,c] = sum_d Wk[d,e] Wq[d,c]
  gemm_f32<1, 0><<<dim3(16, 32), 256, 0, stream>>>(slots, Mt, kq); // kq = slots @ Mt
  gemm_f32<1, 1><<<dim3(16, 32), 256, 0, stream>>>(slots, Wv, vv); // v  = slots @ Wv^T
  scores_topk_k<<<dim3(32, 8), 256, 0, stream>>>(x, kq, topw, topi);
  cvt_bf16_k<<<1024, 256, 0, stream>>>(Wp, WpB);
  gather_k<<<16384, 256, 0, stream>>>(vv, topw, topi, retr);
  gemm_out_k<<<dim3(128, 8), 256, 0, stream>>>(retr, WpB, out);
}

// Round 2
// 581.944 us; speedup vs baseline: 1.0916x; 1.0916x over previous
//
#include <hip/hip_runtime.h>
#include <cstdint>
#include <cstddef>

#define Bb 8
#define Tt 2048
#define Cc 1024
#define Ss 256

using short8 = __attribute__((ext_vector_type(8))) short;
using f32x4  = __attribute__((ext_vector_type(4))) float;

typedef const __attribute__((address_space(1))) void* as1_cvp;
typedef __attribute__((address_space(3))) void* as3_vp;

// round-to-nearest-even fp32 -> bf16 (bit pattern)
__device__ __forceinline__ unsigned short f2bf(float f) {
  unsigned int u = __float_as_uint(f);
  u += 0x7fffu + ((u >> 16) & 1u);
  return (unsigned short)(u >> 16);
}

// slots[b,s,c] = mean over 8 consecutive t rows
__global__ __launch_bounds__(256) void pool_k(const float* __restrict__ x, float* __restrict__ slots) {
  int id = blockIdx.x * 256 + threadIdx.x;   // over B*S*(C/4) = 524288
  int c  = (id & 255) << 2;
  int sl = id >> 8;                          // b*S + s
  int b = sl >> 8, s = sl & 255;
  const float* src = x + ((size_t)b * Tt + s * 8) * Cc + c;
  float ax = 0.f, ay = 0.f, az = 0.f, aw = 0.f;
#pragma unroll
  for (int j = 0; j < 8; j++) {
    float4 v = *(const float4*)(src + (size_t)j * Cc);
    ax += v.x; ay += v.y; az += v.z; aw += v.w;
  }
  float4 o = make_float4(ax * 0.125f, ay * 0.125f, az * 0.125f, aw * 0.125f);
  *(float4*)(slots + (size_t)sl * Cc + c) = o;
}

// fp32 tiled GEMM, 64x64x16 tile, 4x4 microtile. All row strides are 1024, K=1024.
// ATRANS: A stored [M][K]; else A stored [K][M].  BTRANS: B stored [N][K]; else [K][N].
template<int ATRANS, int BTRANS>
__global__ __launch_bounds__(256) void gemm_f32(const float* __restrict__ A, const float* __restrict__ Bm,
                                                float* __restrict__ C) {
  __shared__ float As[16][68];
  __shared__ float Bs[16][68];
  const int tid = threadIdx.x;
  const int m0 = blockIdx.y << 6, n0 = blockIdx.x << 6;
  const int tx = tid & 15, ty = tid >> 4;
  float acc[4][4] = {};
  for (int k0 = 0; k0 < Cc; k0 += 16) {
    __syncthreads();
    if (ATRANS) {
      int m = tid >> 2, k4 = (tid & 3) << 2;
      float4 av = *(const float4*)&A[(size_t)(m0 + m) * Cc + k0 + k4];
      As[k4 + 0][m] = av.x; As[k4 + 1][m] = av.y; As[k4 + 2][m] = av.z; As[k4 + 3][m] = av.w;
    } else {
      int kk = tid >> 4, m4 = (tid & 15) << 2;
      *(float4*)&As[kk][m4] = *(const float4*)&A[(size_t)(k0 + kk) * Cc + m0 + m4];
    }
    if (BTRANS) {
      int n = tid >> 2, k4 = (tid & 3) << 2;
      float4 bv = *(const float4*)&Bm[(size_t)(n0 + n) * Cc + k0 + k4];
      Bs[k4 + 0][n] = bv.x; Bs[k4 + 1][n] = bv.y; Bs[k4 + 2][n] = bv.z; Bs[k4 + 3][n] = bv.w;
    } else {
      int kk = tid >> 4, n4 = (tid & 15) << 2;
      *(float4*)&Bs[kk][n4] = *(const float4*)&Bm[(size_t)(k0 + kk) * Cc + n0 + n4];
    }
    __syncthreads();
#pragma unroll
    for (int kk = 0; kk < 16; kk++) {
      float4 a = *(const float4*)&As[kk][ty << 2];
      float4 b = *(const float4*)&Bs[kk][tx << 2];
      const float aa[4] = {a.x, a.y, a.z, a.w};
      const float bb[4] = {b.x, b.y, b.z, b.w};
#pragma unroll
      for (int i = 0; i < 4; i++)
#pragma unroll
        for (int j = 0; j < 4; j++)
          acc[i][j] = fmaf(aa[i], bb[j], acc[i][j]);
    }
  }
#pragma unroll
  for (int i = 0; i < 4; i++) {
    float4 o = make_float4(acc[i][0], acc[i][1], acc[i][2], acc[i][3]);
    *(float4*)&C[(size_t)(m0 + (ty << 2) + i) * Cc + n0 + (tx << 2)] = o;
  }
}

// scores = x @ kq^T / 32, fused top-8 + softmax. 64 rows x 256 cols per block.
// BK=16, register prefetch. Column ownership: c2=2p+e <-> s = 64p + 2*tx + e
// so kv loads are 4x ds_read_b64 (2-way bank aliasing = free).
__global__ __launch_bounds__(256) void scores_topk_k(const float* __restrict__ x, const float* __restrict__ kq,
                                                     float* __restrict__ topw, int* __restrict__ topi) {
  __shared__ float xs[16][68];
  __shared__ float kqs[16][258];
  const int tid = threadIdx.x;
  const int tt = blockIdx.x, b = blockIdx.y;
  const int tx = tid & 31, ty = tid >> 5;
  const float* xb  = x  + ((size_t)b * Tt + tt * 64) * Cc;
  const float* kqb = kq + (size_t)b * Ss * Cc;
  const int xm = tid >> 2, xk = (tid & 3) << 2;
  const float* xsrc = xb + (size_t)xm * Cc + xk;
  const float* ksrc = kqb + (size_t)tid * Cc;   // s = tid
  float4 px  = *(const float4*)xsrc;
  float4 pk0 = *(const float4*)(ksrc + 0);
  float4 pk1 = *(const float4*)(ksrc + 4);
  float4 pk2 = *(const float4*)(ksrc + 8);
  float4 pk3 = *(const float4*)(ksrc + 12);
  float acc[8][8] = {};
  for (int t64 = 0; t64 < 64; ++t64) {
    __syncthreads();
    xs[xk + 0][xm] = px.x; xs[xk + 1][xm] = px.y; xs[xk + 2][xm] = px.z; xs[xk + 3][xm] = px.w;
    kqs[0][tid]  = pk0.x; kqs[1][tid]  = pk0.y; kqs[2][tid]  = pk0.z; kqs[3][tid]  = pk0.w;
    kqs[4][tid]  = pk1.x; kqs[5][tid]  = pk1.y; kqs[6][tid]  = pk1.z; kqs[7][tid]  = pk1.w;
    kqs[8][tid]  = pk2.x; kqs[9][tid]  = pk2.y; kqs[10][tid] = pk2.z; kqs[11][tid] = pk2.w;
    kqs[12][tid] = pk3.x; kqs[13][tid] = pk3.y; kqs[14][tid] = pk3.z; kqs[15][tid] = pk3.w;
    if (t64 < 63) {
      int k0 = (t64 + 1) << 4;
      px  = *(const float4*)(xsrc + k0);
      pk0 = *(const float4*)(ksrc + k0 + 0);
      pk1 = *(const float4*)(ksrc + k0 + 4);
      pk2 = *(const float4*)(ksrc + k0 + 8);
      pk3 = *(const float4*)(ksrc + k0 + 12);
    }
    __syncthreads();
#pragma unroll
    for (int kk = 0; kk < 16; kk++) {
      float4 xa = *(const float4*)&xs[kk][ty << 2];
      float4 xc = *(const float4*)&xs[kk][32 + (ty << 2)];
      float2 kv0 = *(const float2*)&kqs[kk][(tx << 1)];
      float2 kv1 = *(const float2*)&kqs[kk][64 + (tx << 1)];
      float2 kv2 = *(const float2*)&kqs[kk][128 + (tx << 1)];
      float2 kv3 = *(const float2*)&kqs[kk][192 + (tx << 1)];
      const float xv[8] = {xa.x, xa.y, xa.z, xa.w, xc.x, xc.y, xc.z, xc.w};
      const float kv[8] = {kv0.x, kv0.y, kv1.x, kv1.y, kv2.x, kv2.y, kv3.x, kv3.y};
#pragma unroll
      for (int i = 0; i < 8; i++)
#pragma unroll
        for (int c2 = 0; c2 < 8; c2++)
          acc[i][c2] = fmaf(xv[i], kv[c2], acc[i][c2]);
    }
  }
  // per-row top-8 (lower index wins ties) + softmax, within each 32-lane half-wave
#pragma unroll
  for (int i = 0; i < 8; i++) {
    const int rloc = (i < 4) ? ((ty << 2) + i) : (32 + (ty << 2) + (i - 4));
    float tmp[8];
#pragma unroll
    for (int c2 = 0; c2 < 8; c2++) tmp[c2] = acc[i][c2] * 0.03125f;  // 1/sqrt(1024)
    float topv[8]; int tops[8];
#pragma unroll
    for (int k = 0; k < 8; k++) {
      float bv = -1e30f; int bs = 1 << 20;
#pragma unroll
      for (int c2 = 0; c2 < 8; c2++) {
        float v = tmp[c2];
        int s = (((c2 >> 1) << 6)) + (tx << 1) + (c2 & 1);
        if (v > bv || (v == bv && s < bs)) { bv = v; bs = s; }
      }
#pragma unroll
      for (int m = 16; m >= 1; m >>= 1) {
        float ov = __shfl_xor(bv, m, 64);
        int   os = __shfl_xor(bs, m, 64);
        if (ov > bv || (ov == bv && os < bs)) { bv = ov; bs = os; }
      }
      topv[k] = bv; tops[k] = bs;
#pragma unroll
      for (int c2 = 0; c2 < 8; c2++) {
        int s = (((c2 >> 1) << 6)) + (tx << 1) + (c2 & 1);
        if (s == bs) tmp[c2] = -1e30f;
      }
    }
    float mx = topv[0];
    float sum = 0.f;
#pragma unroll
    for (int k = 0; k < 8; k++) sum += expf(topv[k] - mx);
    if (tx < 8) {
      float myv = topv[0]; int myi = tops[0];
#pragma unroll
      for (int k = 1; k < 8; k++) if (tx == k) { myv = topv[k]; myi = tops[k]; }
      size_t row = (size_t)b * Tt + (size_t)tt * 64 + rloc;
      topw[row * 8 + tx] = expf(myv - mx) / sum;
      topi[row * 8 + tx] = myi;
    }
  }
}

// G[row, :] = sum_k w_k * slots[b, idx_k, :]  -> bf16   (v-path folded into W2)
__global__ __launch_bounds__(256) void gather_k(const float* __restrict__ slots, const float* __restrict__ topw,
                                                const int* __restrict__ topi, unsigned short* __restrict__ G) {
  __shared__ float w[8];
  __shared__ int  id8[8];
  const int row = blockIdx.x;
  const int b = row >> 11;
  if (threadIdx.x < 8) {
    w[threadIdx.x]   = topw[(size_t)row * 8 + threadIdx.x];
    id8[threadIdx.x] = topi[(size_t)row * 8 + threadIdx.x];
  }
  __syncthreads();
  int c = threadIdx.x << 2;
  float ax = 0.f, ay = 0.f, az = 0.f, aw = 0.f;
#pragma unroll
  for (int j = 0; j < 8; j++) {
    const float4 vv = *(const float4*)&slots[((size_t)(b << 8) + id8[j]) * Cc + c];
    float wj = w[j];
    ax = fmaf(wj, vv.x, ax); ay = fmaf(wj, vv.y, ay);
    az = fmaf(wj, vv.z, az); aw = fmaf(wj, vv.w, aw);
  }
  uint2 o;
  o.x = (unsigned)f2bf(ax) | ((unsigned)f2bf(ay) << 16);
  o.y = (unsigned)f2bf(az) | ((unsigned)f2bf(aw) << 16);
  *(uint2*)&G[(size_t)row * Cc + c] = o;
}

__global__ __launch_bounds__(256) void cvt_bf16_k(const float* __restrict__ src, unsigned short* __restrict__ dst) {
  int id = blockIdx.x * 256 + threadIdx.x;
  int c = id << 2;
  float4 v = *(const float4*)&src[c];
  uint2 o;
  o.x = (unsigned)f2bf(v.x) | ((unsigned)f2bf(v.y) << 16);
  o.y = (unsigned)f2bf(v.z) | ((unsigned)f2bf(v.w) << 16);
  *(uint2*)&dst[c] = o;
}

// out = 0.5 * A @ Bw^T, bf16 MFMA 16x16x32, 128x128x32 tile, 4 waves of 64x64.
// Staging via global_load_lds width=16 (m97). LDS rows are 40 shorts = 5x16B
// chunks (4 data + 1 pad); pad chunk gets a duplicate load, never read.
// Row stride 80B -> 2-way bank aliasing on frag ds_read_b128 = free.
__global__ __launch_bounds__(256) void gemm_out_k(const unsigned short* __restrict__ A,
                                                  const unsigned short* __restrict__ Bw,
                                                  float* __restrict__ C) {
  __shared__ unsigned short ABs[1280 * 8];  // 20 KB: A chunks 0..639, B chunks 640..1279
  const int tid = threadIdx.x;
  const int m0 = blockIdx.x << 7, n0 = blockIdx.y << 7;
  const int lane = tid & 63, wid = tid >> 6;
  const int wm = (wid >> 1) << 6, wn = (wid & 1) << 6;
  const int lm = lane & 15, lq = lane >> 4;

  // staging: wave wid covers chunks [wid*320, wid*320+320) via 5 wave-instrs
  const unsigned short* srcp[5];
  int ldsb[5];
#pragma unroll
  for (int i = 0; i < 5; i++) {
    int c = wid * 320 + i * 64 + lane;
    int isB = c >= 640;
    int cc = isB ? c - 640 : c;
    int r = cc / 5;
    int p = cc - r * 5;
    int p4 = (p < 4) ? p : 3;            // junk lane: duplicate last data chunk
    const unsigned short* mat = isB ? Bw : A;
    int r0 = isB ? n0 : m0;
    srcp[i] = mat + (size_t)(r0 + r) * Cc + (p4 << 3);
    ldsb[i] = (wid * 320 + i * 64) << 3; // shorts, wave-uniform
  }

  const f32x4 zero = {0.f, 0.f, 0.f, 0.f};
  f32x4 acc[4][4];
#pragma unroll
  for (int i = 0; i < 4; i++)
#pragma unroll
    for (int j = 0; j < 4; j++) acc[i][j] = zero;

  const unsigned short* Asl = ABs;
  const unsigned short* Bsl = ABs + 640 * 8;

  for (int k0 = 0; k0 < Cc; k0 += 32) {
    __syncthreads();
#pragma unroll
    for (int i = 0; i < 5; i++)
      __builtin_amdgcn_global_load_lds((as1_cvp)(srcp[i] + k0), (as3_vp)&ABs[ldsb[i]], 16, 0, 0);
    __syncthreads();  // barrier drains vmcnt -> LDS filled
    short8 af[4], bf[4];
#pragma unroll
    for (int i = 0; i < 4; i++) af[i] = *(const short8*)&Asl[(wm + (i << 4) + lm) * 40 + (lq << 3)];
#pragma unroll
    for (int j = 0; j < 4; j++) bf[j] = *(const short8*)&Bsl[(wn + (j << 4) + lm) * 40 + (lq << 3)];
#pragma unroll
    for (int i = 0; i < 4; i++)
#pragma unroll
      for (int j = 0; j < 4; j++)
        acc[i][j] = __builtin_amdgcn_mfma_f32_16x16x32_bf16(af[i], bf[j], acc[i][j], 0, 0, 0);
  }
  // C/D layout: col = lane&15, row = (lane>>4)*4 + reg  [m89-verified]
#pragma unroll
  for (int i = 0; i < 4; i++)
#pragma unroll
    for (int j = 0; j < 4; j++)
#pragma unroll
      for (int r = 0; r < 4; r++) {
        int gr = m0 + wm + (i << 4) + (lq << 2) + r;
        int gc = n0 + wn + (j << 4) + lm;
        C[(size_t)gr * Cc + gc] = acc[i][j][r] * 0.5f;
      }
}

extern "C" void kernel_launch(void* const* d_in, const int* in_sizes, int n_in,
                              void* d_out, int out_size, void* d_ws, size_t ws_size,
                              hipStream_t stream) {
  (void)in_sizes; (void)n_in; (void)out_size; (void)ws_size;
  const float* x  = (const float*)d_in[0];
  const float* Wq = (const float*)d_in[1];
  const float* Wk = (const float*)d_in[2];
  const float* Wv = (const float*)d_in[3];
  const float* Wp = (const float*)d_in[4];
  float* out = (float*)d_out;

  char* ws = (char*)d_ws;
  float* slots = (float*)(ws);                                // 8 MB  [2048 x 1024]
  float* Mt    = (float*)(ws + (8ull  << 20));                // 4 MB  Wk^T Wq
  float* kq    = (float*)(ws + (12ull << 20));                // 8 MB  slots @ Mt
  float* W2f   = (float*)(ws + (20ull << 20));                // 4 MB  Wp @ Wv
  float* topw  = (float*)(ws + (24ull << 20));                // 0.5 MB
  int*   topi  = (int*)  (ws + (24ull << 20) + (512u << 10)); // 0.5 MB
  unsigned short* G   = (unsigned short*)(ws + (25ull << 20)); // 32 MB bf16 [16384 x 1024]
  unsigned short* W2B = (unsigned short*)(ws + (57ull << 20)); // 2 MB bf16

  pool_k<<<2048, 256, 0, stream>>>(x, slots);
  gemm_f32<0, 0><<<dim3(16, 16), 256, 0, stream>>>(Wk, Wq, Mt);    // Mt[e,c] = sum_d Wk[d,e] Wq[d,c]
  gemm_f32<1, 0><<<dim3(16, 32), 256, 0, stream>>>(slots, Mt, kq); // kq = slots @ Mt
  gemm_f32<1, 0><<<dim3(16, 16), 256, 0, stream>>>(Wp, Wv, W2f);   // W2[e,c] = sum_d Wp[e,d] Wv[d,c]
  cvt_bf16_k<<<1024, 256, 0, stream>>>(W2f, W2B);
  scores_topk_k<<<dim3(32, 8), 256, 0, stream>>>(x, kq, topw, topi);
  gather_k<<<16384, 256, 0, stream>>>(slots, topw, topi, G);
  gemm_out_k<<<dim3(128, 8), 256, 0, stream>>>(G, W2B, out);
}

// Round 6
// 418.368 us; speedup vs baseline: 1.5184x; 1.3910x over previous
//
#include <hip/hip_runtime.h>
#include <cstdint>
#include <cstddef>

#define Tt 2048
#define Cc 1024
#define Ss 256

using short8 = __attribute__((ext_vector_type(8))) short;
using f32x4  = __attribute__((ext_vector_type(4))) float;
typedef const __attribute__((address_space(1))) void* as1_cvp;
typedef __attribute__((address_space(3))) void* as3_vp;

__device__ __forceinline__ unsigned short f2bf(float f) {
  unsigned int u = __float_as_uint(f);
  u += 0x7fffu + ((u >> 16) & 1u);
  return (unsigned short)(u >> 16);
}
__device__ __forceinline__ float bf2f(unsigned short h) {
  return __uint_as_float(((unsigned)h) << 16);
}
// 3-way split: v = h + m + l to ~2^-24 relative
__device__ __forceinline__ void split3(float v, unsigned short& h, unsigned short& m, unsigned short& l) {
  h = f2bf(v);
  float r = v - bf2f(h);
  m = f2bf(r);
  l = f2bf(r - bf2f(m));
}

// LDS short-offset for 64-row x 32-short tile, chunk-XOR swizzled (2-way bank
// aliasing on ds_read_b128 = free, m136)
__device__ __forceinline__ int sw32(int row, int q) {
  return row * 32 + ((q ^ ((row >> 1) & 3)) << 3);
}

// slots planes = split3(mean over 8 consecutive t rows)
__global__ __launch_bounds__(256) void poolsplit_k(const float* __restrict__ x, unsigned short* __restrict__ sp) {
  const long PS2 = 2048l * 1024;
  const int sli = blockIdx.x;           // b*256+s
  const int c = threadIdx.x << 2;
  const float* src = x + (size_t)sli * 8 * Cc + c;
  float a[4] = {0.f, 0.f, 0.f, 0.f};
#pragma unroll
  for (int j = 0; j < 8; j++) {
    float4 v = *(const float4*)(src + (size_t)j * Cc);
    a[0] += v.x; a[1] += v.y; a[2] += v.z; a[3] += v.w;
  }
  unsigned short h[4], m[4], l[4];
#pragma unroll
  for (int e = 0; e < 4; e++) split3(a[e] * 0.125f, h[e], m[e], l[e]);
  size_t o = (size_t)sli * Cc + c;
  *(uint2*)&sp[o]           = uint2{(unsigned)h[0] | ((unsigned)h[1] << 16), (unsigned)h[2] | ((unsigned)h[3] << 16)};
  *(uint2*)&sp[o + PS2]     = uint2{(unsigned)m[0] | ((unsigned)m[1] << 16), (unsigned)m[2] | ((unsigned)m[3] << 16)};
  *(uint2*)&sp[o + 2 * PS2] = uint2{(unsigned)l[0] | ((unsigned)l[1] << 16), (unsigned)l[2] | ((unsigned)l[3] << 16)};
}

// Transpose + split: dst[p][e][d] = split3(src[d][e]), npl planes written.
__global__ __launch_bounds__(256) void split_t_k(const float* __restrict__ src, unsigned short* __restrict__ dst,
                                                 long pstride, int npl) {
  __shared__ unsigned short th[64][68], tm[64][68], tl[64][68];
  const int r0 = blockIdx.y << 6, c0 = blockIdx.x << 6;
  const int tid = threadIdx.x;
#pragma unroll
  for (int p = 0; p < 4; p++) {
    int r = (p << 4) + (tid >> 4);
    int c = (tid & 15) << 2;
    float4 v = *(const float4*)&src[(size_t)(r0 + r) * Cc + c0 + c];
    unsigned short h, m, l;
    split3(v.x, h, m, l); th[c + 0][r] = h; tm[c + 0][r] = m; tl[c + 0][r] = l;
    split3(v.y, h, m, l); th[c + 1][r] = h; tm[c + 1][r] = m; tl[c + 1][r] = l;
    split3(v.z, h, m, l); th[c + 2][r] = h; tm[c + 2][r] = m; tl[c + 2][r] = l;
    split3(v.w, h, m, l); th[c + 3][r] = h; tm[c + 3][r] = m; tl[c + 3][r] = l;
  }
  __syncthreads();
#pragma unroll
  for (int p = 0; p < 4; p++) {
    int r = (p << 4) + (tid >> 4);      // dst row = src col
    int c = (tid & 15) << 2;
    size_t o = (size_t)(c0 + r) * Cc + r0 + c;
    *(uint2*)&dst[o] = uint2{(unsigned)th[r][c] | ((unsigned)th[r][c+1] << 16),
                             (unsigned)th[r][c+2] | ((unsigned)th[r][c+3] << 16)};
    *(uint2*)&dst[o + pstride] = uint2{(unsigned)tm[r][c] | ((unsigned)tm[r][c+1] << 16),
                                       (unsigned)tm[r][c+2] | ((unsigned)tm[r][c+3] << 16)};
    if (npl == 3)
      *(uint2*)&dst[o + 2 * pstride] = uint2{(unsigned)tl[r][c] | ((unsigned)tl[r][c+1] << 16),
                                             (unsigned)tl[r][c+2] | ((unsigned)tl[r][c+3] << 16)};
  }
}

// Plain split, npl planes
__global__ __launch_bounds__(256) void split_k(const float* __restrict__ src, unsigned short* __restrict__ dst,
                                               long pstride, int npl) {
  int id = blockIdx.x * 256 + threadIdx.x;
  int c = id << 2;
  float4 v = *(const float4*)&src[c];
  unsigned short h[4], m[4], l[4];
  split3(v.x, h[0], m[0], l[0]); split3(v.y, h[1], m[1], l[1]);
  split3(v.z, h[2], m[2], l[2]); split3(v.w, h[3], m[3], l[3]);
  *(uint2*)&dst[c] = uint2{(unsigned)h[0] | ((unsigned)h[1] << 16), (unsigned)h[2] | ((unsigned)h[3] << 16)};
  *(uint2*)&dst[c + pstride] = uint2{(unsigned)m[0] | ((unsigned)m[1] << 16), (unsigned)m[2] | ((unsigned)m[3] << 16)};
  if (npl == 3)
    *(uint2*)&dst[c + 2 * pstride] = uint2{(unsigned)l[0] | ((unsigned)l[1] << 16), (unsigned)l[2] | ((unsigned)l[3] << 16)};
}

// Multi-plane split GEMM body: C = scale * A @ B^T with A,B as NPL bf16 planes.
// NT=6: products hh,hm,mh,hl,lh,mm (error ~2^-24). NT=3: hh,hm,mh (~2^-16).
// 64x64 tile, BK=32, 4 waves of 32x32. global_load_lds width-16 staging.
// NOTE: wrapped in concrete __global__ kernels below — template __global__
// kernels fail to emit host stubs in this shared-lib build (round-5 link error).
template<int NT, int SPLIT_OUT>
__device__ __forceinline__ void gemm3_body(const unsigned short* __restrict__ Ap, long apl,
                                           const unsigned short* __restrict__ Bp, long bpl,
                                           float* __restrict__ C,
                                           unsigned short* __restrict__ Cs, long cpl,
                                           float scale) {
  constexpr int NPL = (NT == 6) ? 3 : 2;
  __shared__ unsigned short LDS[2 * NPL * 2048];  // A planes then B planes
  const int tid = threadIdx.x, lane = tid & 63, wid = tid >> 6;
  const int m0 = blockIdx.y << 6, n0 = blockIdx.x << 6;

  const unsigned short* sp[2 * NPL];
  as3_vp dst[2 * NPL];
#pragma unroll
  for (int i = 0; i < 2 * NPL; i++) {
    int s = wid * 2 * NPL + i;           // [0, 8*NPL)
    int tile = s >> 2;                   // [0, 2*NPL)
    int ci = ((s & 3) << 6) | lane;      // chunk in tile [0,256)
    int row = ci >> 2;
    int q = (ci & 3) ^ ((row >> 1) & 3); // source chunk for swizzled slot
    int isB = tile >= NPL;
    int pl = isB ? tile - NPL : tile;
    const unsigned short* base = isB ? (Bp + (size_t)pl * bpl) : (Ap + (size_t)pl * apl);
    int r0 = isB ? n0 : m0;
    sp[i] = base + (size_t)(r0 + row) * Cc + (q << 3);
    dst[i] = (as3_vp)(LDS + tile * 2048 + ((s & 3) << 9));
  }

  const int wm = (wid >> 1) << 5, wn = (wid & 1) << 5;
  const int lm = lane & 15, lq = lane >> 4;
  constexpr int PA[6] = {0, 0, 1, 0, 2, 1};
  constexpr int PB[6] = {0, 1, 0, 2, 0, 1};
  const f32x4 zero = {0.f, 0.f, 0.f, 0.f};
  f32x4 acc[2][2] = {{zero, zero}, {zero, zero}};

  for (int k0 = 0; k0 < Cc; k0 += 32) {
    __syncthreads();
#pragma unroll
    for (int i = 0; i < 2 * NPL; i++) {
      __builtin_amdgcn_global_load_lds((as1_cvp)sp[i], dst[i], 16, 0, 0);
      sp[i] += 32;
    }
    __syncthreads();
    short8 af[2][NPL], bf[2][NPL];
#pragma unroll
    for (int i = 0; i < 2; i++)
#pragma unroll
      for (int p = 0; p < NPL; p++) {
        af[i][p] = *(const short8*)&LDS[p * 2048 + sw32(wm + (i << 4) + lm, lq)];
        bf[i][p] = *(const short8*)&LDS[(NPL + p) * 2048 + sw32(wn + (i << 4) + lm, lq)];
      }
#pragma unroll
    for (int i = 0; i < 2; i++)
#pragma unroll
      for (int j = 0; j < 2; j++)
#pragma unroll
        for (int t = 0; t < NT; t++)
          acc[i][j] = __builtin_amdgcn_mfma_f32_16x16x32_bf16(af[i][PA[t]], bf[j][PB[t]], acc[i][j], 0, 0, 0);
  }
  // C/D: col = lane&15, row = (lane>>4)*4 + reg  [m89-verified]
#pragma unroll
  for (int i = 0; i < 2; i++)
#pragma unroll
    for (int j = 0; j < 2; j++)
#pragma unroll
      for (int r = 0; r < 4; r++) {
        int gr = m0 + wm + (i << 4) + (lq << 2) + r;
        int gc = n0 + wn + (j << 4) + lm;
        size_t o = (size_t)gr * Cc + gc;
        float v = acc[i][j][r] * scale;
        if (SPLIT_OUT) {
          unsigned short h = f2bf(v);
          float rr = v - bf2f(h);
          unsigned short mm2 = f2bf(rr);
          Cs[o] = h;
          Cs[o + cpl] = mm2;
          if (NPL == 3) Cs[o + 2 * (size_t)cpl] = f2bf(rr - bf2f(mm2));
        } else {
          C[o] = v;
        }
      }
}

// Concrete wrappers (no template __global__ — see round-5 link failure)
__global__ __launch_bounds__(256) void gemm3_61_k(const unsigned short* __restrict__ Ap, long apl,
                                                  const unsigned short* __restrict__ Bp, long bpl,
                                                  unsigned short* __restrict__ Cs, long cpl, float scale) {
  gemm3_body<6, 1>(Ap, apl, Bp, bpl, nullptr, Cs, cpl, scale);
}
__global__ __launch_bounds__(256) void gemm3_31_k(const unsigned short* __restrict__ Ap, long apl,
                                                  const unsigned short* __restrict__ Bp, long bpl,
                                                  unsigned short* __restrict__ Cs, long cpl, float scale) {
  gemm3_body<3, 1>(Ap, apl, Bp, bpl, nullptr, Cs, cpl, scale);
}
__global__ __launch_bounds__(256) void gemm3_30_k(const unsigned short* __restrict__ Ap, long apl,
                                                  const unsigned short* __restrict__ Bp, long bpl,
                                                  float* __restrict__ C, float scale) {
  gemm3_body<3, 0>(Ap, apl, Bp, bpl, C, nullptr, 0, scale);
}

// Fused scores + top-8 + softmax. 64 t-rows x 256 slots per block, 512 thr
// (8 waves of 32x64). BK=32: stage x fp32 + kq 3 planes via global_load_lds;
// VALU split3 of x into padded LDS planes; 6-product split MFMA (~2^-24).
__global__ __launch_bounds__(512) void scores_topk_k(const float* __restrict__ x,
                                                     const unsigned short* __restrict__ kqp,
                                                     float* __restrict__ topw, int* __restrict__ topi) {
  __shared__ __align__(16) char smem[71168];
  float* xf = (float*)smem;                         // [0,8192) 64x32 fp32 linear
  // kq planes: 8192 + p*16384 (256 rows x 32 bf16, swizzled)
  // x planes:  57344 + p*4608 (64 rows x 36 bf16, padded)
  unsigned short* lds16 = (unsigned short*)smem;
  float* sc = (float*)smem;                         // tail: 64x260 fp32

  const int tid = threadIdx.x, lane = tid & 63, wid = tid >> 6;
  const int tt = blockIdx.x, b = blockIdx.y;
  const float* xb = x + ((size_t)b * Tt + (size_t)tt * 64) * Cc;

  const char* srcs[7]; int step[7]; as3_vp ldst[7];
#pragma unroll
  for (int i = 0; i < 7; i++) {
    int s = wid * 7 + i;                 // [0,56)
    if (s < 8) {
      int ci = (s << 6) | lane;          // [0,512)
      int row = ci >> 3, off = (ci & 7) << 2;
      srcs[i] = (const char*)(xb + (size_t)row * Cc + off);
      step[i] = 128;
      ldst[i] = (as3_vp)(smem + s * 1024);
    } else {
      int p = (s - 8) >> 4;              // plane 0..2
      int sub = (s - 8) & 15;
      int ci = (sub << 6) | lane;        // [0,1024)
      int row = ci >> 2;
      int q = (ci & 3) ^ ((row >> 1) & 3);
      const unsigned short* kb = kqp + (size_t)p * (2048l * 1024) + (size_t)b * Ss * Cc;
      srcs[i] = (const char*)(kb + (size_t)row * Cc + (q << 3));
      step[i] = 64;
      ldst[i] = (as3_vp)(smem + 8192 + p * 16384 + (sub << 10));
    }
  }

  const int wm = (wid & 1) << 5;         // row group
  const int wn = (wid >> 1) << 6;        // col group (x4)
  const int lm = lane & 15, lq = lane >> 4;
  const int spr = tid >> 3, spk = (tid & 7) << 2;
  const int XS = 28672;                  // x-plane base (shorts), plane stride 2304

  constexpr int PA[6] = {0, 0, 1, 0, 2, 1};
  constexpr int PB[6] = {0, 1, 0, 2, 0, 1};
  const f32x4 zero = {0.f, 0.f, 0.f, 0.f};
  f32x4 acc[2][4];
#pragma unroll
  for (int i = 0; i < 2; i++)
#pragma unroll
    for (int j = 0; j < 4; j++) acc[i][j] = zero;

  for (int ks = 0; ks < 32; ks++) {
    __syncthreads();
#pragma unroll
    for (int i = 0; i < 7; i++) {
      __builtin_amdgcn_global_load_lds((as1_cvp)srcs[i], ldst[i], 16, 0, 0);
      srcs[i] += step[i];
    }
    __syncthreads();
    {  // split3 of x tile: 4 fp32/thread
      float4 v = *(const float4*)(xf + (tid << 2));
      unsigned short h[4], m[4], l[4];
      split3(v.x, h[0], m[0], l[0]); split3(v.y, h[1], m[1], l[1]);
      split3(v.z, h[2], m[2], l[2]); split3(v.w, h[3], m[3], l[3]);
      int o = XS + spr * 36 + spk;
      *(uint2*)&lds16[o]        = uint2{(unsigned)h[0] | ((unsigned)h[1] << 16), (unsigned)h[2] | ((unsigned)h[3] << 16)};
      *(uint2*)&lds16[o + 2304] = uint2{(unsigned)m[0] | ((unsigned)m[1] << 16), (unsigned)m[2] | ((unsigned)m[3] << 16)};
      *(uint2*)&lds16[o + 4608] = uint2{(unsigned)l[0] | ((unsigned)l[1] << 16), (unsigned)l[2] | ((unsigned)l[3] << 16)};
    }
    __syncthreads();
    short8 afr[2][3], bfr[4][3];
#pragma unroll
    for (int i = 0; i < 2; i++)
#pragma unroll
      for (int p = 0; p < 3; p++)
        afr[i][p] = *(const short8*)&lds16[XS + p * 2304 + (wm + (i << 4) + lm) * 36 + (lq << 3)];
#pragma unroll
    for (int j = 0; j < 4; j++) {
      int br = wn + (j << 4) + lm;
      int bo = (br << 5) + ((lq ^ ((br >> 1) & 3)) << 3);
#pragma unroll
      for (int p = 0; p < 3; p++)
        bfr[j][p] = *(const short8*)&lds16[4096 + p * 8192 + bo];
    }
#pragma unroll
    for (int i = 0; i < 2; i++)
#pragma unroll
      for (int j = 0; j < 4; j++)
#pragma unroll
        for (int t = 0; t < 6; t++)
          acc[i][j] = __builtin_amdgcn_mfma_f32_16x16x32_bf16(afr[i][PA[t]], bfr[j][PB[t]], acc[i][j], 0, 0, 0);
  }

  // scores -> LDS (scaled 1/32), then per-wave top-8 + softmax
  __syncthreads();
#pragma unroll
  for (int i = 0; i < 2; i++)
#pragma unroll
    for (int j = 0; j < 4; j++)
#pragma unroll
      for (int r = 0; r < 4; r++)
        sc[(wm + (i << 4) + (lq << 2) + r) * 260 + wn + (j << 4) + lm] = acc[i][j][r] * 0.03125f;
  __syncthreads();

  for (int r2 = 0; r2 < 8; r2++) {
    int row = (wid << 3) + r2;
    float4 v = *(const float4*)(sc + row * 260 + (lane << 2));
    float cand[4] = {v.x, v.y, v.z, v.w};
    float topv[8]; int tops[8];
#pragma unroll
    for (int k = 0; k < 8; k++) {
      float bv = -1e30f; int bs = 1 << 20;
#pragma unroll
      for (int e = 0; e < 4; e++) {
        int s = (lane << 2) + e;
        if (cand[e] > bv || (cand[e] == bv && s < bs)) { bv = cand[e]; bs = s; }
      }
#pragma unroll
      for (int m = 32; m >= 1; m >>= 1) {
        float ov = __shfl_xor(bv, m, 64);
        int   os = __shfl_xor(bs, m, 64);
        if (ov > bv || (ov == bv && os < bs)) { bv = ov; bs = os; }
      }
      topv[k] = bv; tops[k] = bs;
      if ((bs >> 2) == lane) cand[bs & 3] = -1e30f;
    }
    float mx = topv[0];
    float sum = 0.f;
#pragma unroll
    for (int k = 0; k < 8; k++) sum += expf(topv[k] - mx);
    if (lane < 8) {
      float myv = topv[0]; int myi = tops[0];
#pragma unroll
      for (int k = 1; k < 8; k++) if (lane == k) { myv = topv[k]; myi = tops[k]; }
      size_t trow = (size_t)b * Tt + (size_t)tt * 64 + row;
      topw[trow * 8 + lane] = expf(myv - mx) / sum;
      topi[trow * 8 + lane] = myi;
    }
  }
}

// out[row,:] = 0.5 * sum_k w_k * u[b*256+idx_k, :]   (fp32)
__global__ __launch_bounds__(256) void gatherout_k(const float* __restrict__ u, const float* __restrict__ topw,
                                                   const int* __restrict__ topi, float* __restrict__ out) {
  __shared__ float w[8];
  __shared__ int  id8[8];
  const int row = blockIdx.x;
  const int b = row >> 11;
  if (threadIdx.x < 8) {
    w[threadIdx.x]   = topw[(size_t)row * 8 + threadIdx.x];
    id8[threadIdx.x] = topi[(size_t)row * 8 + threadIdx.x];
  }
  __syncthreads();
  int c = threadIdx.x << 2;
  float ax = 0.f, ay = 0.f, az = 0.f, aw = 0.f;
#pragma unroll
  for (int j = 0; j < 8; j++) {
    const float4 vv = *(const float4*)&u[((size_t)(b << 8) + id8[j]) * Cc + c];
    float wj = w[j];
    ax = fmaf(wj, vv.x, ax); ay = fmaf(wj, vv.y, ay);
    az = fmaf(wj, vv.z, az); aw = fmaf(wj, vv.w, aw);
  }
  *(float4*)&out[(size_t)row * Cc + c] = make_float4(ax * 0.5f, ay * 0.5f, az * 0.5f, aw * 0.5f);
}

extern "C" void kernel_launch(void* const* d_in, const int* in_sizes, int n_in,
                              void* d_out, int out_size, void* d_ws, size_t ws_size,
                              hipStream_t stream) {
  (void)in_sizes; (void)n_in; (void)out_size; (void)ws_size;
  const float* x  = (const float*)d_in[0];
  const float* Wq = (const float*)d_in[1];
  const float* Wk = (const float*)d_in[2];
  const float* Wv = (const float*)d_in[3];
  const float* Wp = (const float*)d_in[4];
  float* out = (float*)d_out;

  char* ws = (char*)d_ws;
  const size_t MB = 1ull << 20;
  const long PS1 = 1024l * 1024;   // plane stride, 1024x1024 (shorts)
  const long PS2 = 2048l * 1024;   // plane stride, 2048x1024 (shorts)
  unsigned short* slotp = (unsigned short*)(ws + 0 * MB);   // 12 MB: 3 planes [2048x1024]
  unsigned short* Wqt   = (unsigned short*)(ws + 12 * MB);  // 6 MB: 3 planes [c][d]
  unsigned short* Wkt   = (unsigned short*)(ws + 18 * MB);  // 6 MB: 3 planes [e][d]
  unsigned short* Wvt   = (unsigned short*)(ws + 24 * MB);  // 4 MB: 2 planes [e][d]
  unsigned short* Wpp   = (unsigned short*)(ws + 28 * MB);  // 4 MB: 2 planes [o][d]
  unsigned short* MtT   = (unsigned short*)(ws + 32 * MB);  // 6 MB: 3 planes [c][e] = (Wk^T Wq)^T
  unsigned short* kqp   = (unsigned short*)(ws + 38 * MB);  // 12 MB: 3 planes [2048x1024]
  unsigned short* W2p   = (unsigned short*)(ws + 50 * MB);  // 4 MB: 2 planes [o][e] = Wp@Wv
  float*          u     = (float*)(ws + 54 * MB);           // 8 MB fp32 [2048x1024]
  float*          topw  = (float*)(ws + 62 * MB);           // 0.5 MB
  int*            topi  = (int*)(ws + 62 * MB + 512 * 1024);// 0.5 MB -> 63 MB total (<=113 validated)

  // 1. pool + split3 slots (x read once here)
  poolsplit_k<<<2048, 256, 0, stream>>>(x, slotp);
  // 2. transpose+split weights
  split_t_k<<<dim3(16, 16), 256, 0, stream>>>(Wq, Wqt, PS1, 3);
  split_t_k<<<dim3(16, 16), 256, 0, stream>>>(Wk, Wkt, PS1, 3);
  split_t_k<<<dim3(16, 16), 256, 0, stream>>>(Wv, Wvt, PS1, 2);
  split_k<<<1024, 256, 0, stream>>>(Wp, Wpp, PS1, 2);
  // 3. MtT[c][e] = sum_d Wq[d][c]*Wk[d][e]   (6-product, split3 out)
  gemm3_61_k<<<dim3(16, 16), 256, 0, stream>>>(Wqt, PS1, Wkt, PS1, MtT, PS1, 1.0f);
  // 4. kq[s][c] = sum_e slots[s][e]*MtT[c][e] (6-product, split3 out)
  gemm3_61_k<<<dim3(16, 32), 256, 0, stream>>>(slotp, PS2, MtT, PS1, kqp, PS2, 1.0f);
  // 5. W2[o][e] = sum_d Wp[o][d]*Wvt[e][d]    (3-product, split2 out)
  gemm3_31_k<<<dim3(16, 16), 256, 0, stream>>>(Wpp, PS1, Wvt, PS1, W2p, PS1, 1.0f);
  // 6. u[s][o] = sum_e slots[s][e]*W2[o][e]   (3-product, fp32 out)
  gemm3_30_k<<<dim3(16, 32), 256, 0, stream>>>(slotp, PS2, W2p, PS1, u, 1.0f);
  // 7. fused scores (6-product) + top-8 + softmax
  scores_topk_k<<<dim3(32, 8), 512, 0, stream>>>(x, kqp, topw, topi);
  // 8. gather + 0.5 scale
  gatherout_k<<<16384, 256, 0, stream>>>(u, topw, topi, out);
}